// Round 5
// baseline (480.609 us; speedup 1.0000x reference)
//
#include <hip/hip_runtime.h>

// ---------------------------------------------------------------------------
// Attention (B=32,N=577,C=768,H=12,D=64) with RoPE, fp32 I/O, bf16 MFMA core.
// R13: attn split-KV. Diagnosis (first attn counters): MfmaUtil 10%, VALUBusy
// 15%, HBM 6%, Occupancy 29% => latency-bound serial 10-tile chain per wave,
// too few resident waves. Fixed-max softmax makes O,l pure sums over kv =>
// split-K combine is an elementwise add. New attn: 512 threads = 8 waves;
// wave w = (qslice w&3, kvhalf w>>2), 5 tiles each; LDS combine (reusing the
// P slabs); epilogue on waves 0-3 unchanged. gemm1/gemm2/vtrans from R12.
// ---------------------------------------------------------------------------

#define M_ROWS 18464          // B*N
#define M_PAD  18560          // 145*128
#define CDIM   768
#define QKVN   2304
#define NHEADS 12
#define BHEADS 384            // B*H
#define NSEQ   577
#define NPAD   640            // 10*64
#define SCALE  0.125f

typedef __bf16 bf16x8 __attribute__((ext_vector_type(8)));
typedef __bf16 bf16x4 __attribute__((ext_vector_type(4)));
typedef float  f32x4  __attribute__((ext_vector_type(4)));

typedef const __attribute__((address_space(1))) void* gas_ptr;
typedef __attribute__((address_space(3))) void* las_ptr;

__device__ inline void gload16(const __bf16* g, __bf16* l) {
  __builtin_amdgcn_global_load_lds((gas_ptr)g, (las_ptr)l, 16, 0, 0);
}

// m204 bijective chunked XCD swizzle
__device__ inline int xcd_swizzle(int orig, int nwg) {
  int q = nwg >> 3, r = nwg & 7;
  int xcd = orig & 7, idx = orig >> 3;
  int base = (xcd < r) ? xcd * (q + 1) : r * (q + 1) + (xcd - r) * q;
  return base + idx;
}

// ------------------------- converts / padding ------------------------------

__global__ void cvt_pad(const float* __restrict__ src, __bf16* __restrict__ dst,
                        long n_src, long n_dst) {
  long i = ((long)blockIdx.x * 256 + threadIdx.x) * 4;
  if (i >= n_dst) return;
  if (i + 3 < n_src) {
    f32x4 v = *(const f32x4*)(src + i);
    bf16x4 o = {(__bf16)v[0], (__bf16)v[1], (__bf16)v[2], (__bf16)v[3]};
    *(bf16x4*)(dst + i) = o;
  } else {
#pragma unroll
    for (int j = 0; j < 4; j++)
      if (i + j < n_dst) dst[i + j] = (i + j < n_src) ? (__bf16)src[i + j] : (__bf16)0.0f;
  }
}

// zero the seq-padding region (s in [577,640)) of q, k  (vT pad handled by vtrans)
__global__ void pad_zero(__bf16* __restrict__ q, __bf16* __restrict__ k) {
  int i = blockIdx.x * 256 + threadIdx.x;
  if (i >= BHEADS * 63 * 64) return;
  int d = i & 63;
  int t = i >> 6;
  int sp = t % 63, bh = t / 63;
  int s = NSEQ + sp;
  q[((size_t)bh * NPAD + s) * 64 + d] = (__bf16)0.0f;
  k[((size_t)bh * NPAD + s) * 64 + d] = (__bf16)0.0f;
}

// ------------------------- GEMM1: x @ w_qkv^T + RoPE -----------------------
// K-loop: 3-buffer 2-deep prefetch, counted vmcnt(4), raw barriers (R10/R11).
// Epilogue (R12): phase A = f32 RoPE -> LDS tile [128][136]; phase B =
// coalesced bf16x8 stores. V stored ROW-major into vr.

#define G1_NWG (18 * 145)

__launch_bounds__(256, 2)
__global__ void gemm1(const __bf16* __restrict__ A, const __bf16* __restrict__ Bw,
                      __bf16* __restrict__ qq, __bf16* __restrict__ kk,
                      __bf16* __restrict__ vr,
                      const float* __restrict__ cs, const float* __restrict__ sn) {
  __shared__ __bf16 smem[3 * 4096 * 2];   // As[3] | Bs[3], reused as out-tile
  const int wgid = xcd_swizzle(blockIdx.x, G1_NWG);
  const int bn = wgid % 18, bm = wgid / 18;
  const int tid = threadIdx.x;
  const int w = tid >> 6, lane = tid & 63;
  const int lr = lane & 15, quad = lane >> 4;
  const int r0 = tid >> 2;
  const int kq = (tid & 3) * 8;
  const int K = CDIM;

  f32x4 acc[4][4] = {};
  const __bf16* Ab = A + (size_t)(bm * 128 + r0) * K + kq;
  const __bf16* Bb = Bw + (size_t)(bn * 128 + r0) * K + kq;
  const int wm = (w >> 1) * 64, wn = (w & 1) * 64;

  auto stage = [&](int kt, int buf) __attribute__((always_inline)) {
    gload16(Ab + kt, &smem[buf * 4096 + tid * 8]);
    gload16(Ab + kt + 64 * K, &smem[buf * 4096 + tid * 8 + 2048]);
    gload16(Bb + kt, &smem[12288 + buf * 4096 + tid * 8]);
    gload16(Bb + kt + 64 * K, &smem[12288 + buf * 4096 + tid * 8 + 2048]);
  };

  stage(0, 0);
  stage(32, 1);
  asm volatile("s_waitcnt vmcnt(4)" ::: "memory");
  asm volatile("s_barrier" ::: "memory");

  int c0 = 0, c1 = 1, c2 = 2;
#pragma unroll 1
  for (int kt = 0; kt < K; kt += 32) {
    if (kt + 64 < K) stage(kt + 64, c2);

    bf16x8 af[4], bfr[4];
#pragma unroll
    for (int i = 0; i < 4; i++) {
      af[i]  = *(const bf16x8*)&smem[c0 * 4096 + (wm + i * 16 + lr) * 32 + quad * 8];
      bfr[i] = *(const bf16x8*)&smem[12288 + c0 * 4096 + (wn + i * 16 + lr) * 32 + quad * 8];
    }
#pragma unroll
    for (int i = 0; i < 4; i++)
#pragma unroll
      for (int j = 0; j < 4; j++)
        acc[i][j] = __builtin_amdgcn_mfma_f32_16x16x32_bf16(af[i], bfr[j], acc[i][j], 0, 0, 0);

    if (kt + 64 < K)      asm volatile("s_waitcnt vmcnt(4)" ::: "memory");
    else if (kt + 32 < K) asm volatile("s_waitcnt vmcnt(0)" ::: "memory");
    asm volatile("s_barrier" ::: "memory");

    int tmp = c0; c0 = c1; c1 = c2; c2 = tmp;
  }

  // ---------------- epilogue: LDS bounce ----------------
  __syncthreads();
  __bf16* tile = smem;                // [128][136] bf16
  const bool isv = (bn >= 12);

#pragma unroll
  for (int i = 0; i < 4; i++) {
#pragma unroll
    for (int r = 0; r < 4; r++) {
      int ml = wm + i * 16 + quad * 4 + r;
      int m = bm * 128 + ml;
      int s = 0;
      if (!isv) { int b = m / NSEQ; s = m - b * NSEQ; }
#pragma unroll
      for (int j = 0; j < 4; j++) {
        int nl = wn + j * 16 + lr;
        float v = acc[i][j][r];
        float outv = v;
        if (!isv) {
          float pv = __shfl_xor(v, 1, 64);
          if (s >= 1 && m < M_ROWS) {
            int d = nl & 63;
            float c  = cs[(size_t)(s - 1) * 32 + (d >> 1)];
            float sv = sn[(size_t)(s - 1) * 32 + (d >> 1)];
            outv = (nl & 1) ? (pv * sv + v * c) : (v * c - pv * sv);
          }
        }
        tile[ml * 136 + nl] = (__bf16)outv;
      }
    }
  }
  __syncthreads();

  {
    const int tq = tid >> 4, tc = tid & 15;
    const int t_blk = bn / 6;             // 0=q 1=k 2=v
    const int bnq = bn % 6;
    __bf16* dstb = (t_blk == 0) ? qq : (t_blk == 1) ? kk : vr;
    const int SS = (t_blk == 2) ? NSEQ : NPAD;
    const int h = bnq * 2 + (tc >> 3);
    const int d0 = (tc & 7) * 8;
#pragma unroll
    for (int p = 0; p < 8; p++) {
      int ml = p * 16 + tq;
      int m = bm * 128 + ml;
      if (m < M_ROWS) {
        int b = m / NSEQ, s = m - b * NSEQ;
        bf16x8 val = *(const bf16x8*)&tile[ml * 136 + tc * 8];
        *(bf16x8*)&dstb[(((size_t)(b * NHEADS + h) * SS + s) << 6) + d0] = val;
      }
    }
  }
}

// -------- vtrans: vr [bh][s<577][d] -> vT [bh][d][s_pad 640] (zero pad) ----

__global__ void vtrans(const __bf16* __restrict__ vr, __bf16* __restrict__ vt) {
  __shared__ __bf16 t[64 * 72];
  int blk = blockIdx.x;
  int bh = blk / 10, sc = blk % 10;
  int tid = threadIdx.x;
  int ts = tid >> 2;
  int dc = (tid & 3) * 16;
  int s = sc * 64 + ts;
  bf16x8 a = {}, b2 = {};
  if (s < NSEQ) {
    const __bf16* src = vr + ((size_t)bh * NSEQ + s) * 64 + dc;
    a  = *(const bf16x8*)src;
    b2 = *(const bf16x8*)(src + 8);
  }
#pragma unroll
  for (int e = 0; e < 8; e++) {
    t[(dc + e) * 72 + ts]     = a[e];
    t[(dc + 8 + e) * 72 + ts] = b2[e];
  }
  __syncthreads();
  int d = tid >> 2;
  int scol = (tid & 3) * 16;
  bf16x8 o0 = *(const bf16x8*)&t[d * 72 + scol];
  bf16x8 o1 = *(const bf16x8*)&t[d * 72 + scol + 8];
  __bf16* dst = vt + ((size_t)bh * 64 + d) * NPAD + sc * 64 + scol;
  *(bf16x8*)dst = o0;
  *(bf16x8*)(dst + 8) = o1;
}

// --------------------- flash attention (fixed-max, split-KV) ---------------
// 8 waves: wave w = (qslice qs=w&3, kvhalf=w>>2). Each wave runs 5 kv tiles;
// fixed-max softmax => O,l are pure sums => halves combine by elementwise add
// in LDS (P slabs reused). Epilogue identical to R12, on waves 0-3.

#define AT_NWG (BHEADS * 5)

__launch_bounds__(512, 4)
__global__ void attn(const __bf16* __restrict__ q, const __bf16* __restrict__ k,
                     const __bf16* __restrict__ vT, __bf16* __restrict__ aoh) {
  __shared__ float Xf[8][1152];          // 36,864 B: P slabs / combine buffer
  const int blk = xcd_swizzle(blockIdx.x, AT_NWG);
  const int qt5 = blk % 5, bh = blk / 5;
  const int b = bh / NHEADS, h = bh % NHEADS;
  const int w = threadIdx.x >> 6, lane = threadIdx.x & 63;
  const int qs = w & 3, half = w >> 2;
  const int lr = lane & 15, quad = lane >> 4;
  const int qbase = qt5 * 128 + qs * 32;

  float* xw = &Xf[w][0];
  __bf16* pw = (__bf16*)xw;

  // Q fragments (B-operand): B[n = q-col = lr][k = d = quad*8+j]
  bf16x8 qf[2][2];
#pragma unroll
  for (int qt = 0; qt < 2; qt++)
#pragma unroll
    for (int kh = 0; kh < 2; kh++)
      qf[qt][kh] = *(const bf16x8*)(q + ((size_t)bh * NPAD + qbase + qt * 16 + lr) * 64 + kh * 32 + quad * 8);

  f32x4 O[2][4] = {};
  float l_p[2] = {0.0f, 0.0f};
  const float C1 = SCALE * 1.44269504089f;
  const float C0 = -8.0f * 1.44269504089f;
  const __bf16* kbase = k + (size_t)bh * NPAD * 64;
  const __bf16* vbase = vT + (size_t)bh * 64 * NPAD;

  auto tile = [&](int kv0, bool masked) __attribute__((always_inline)) {
    bf16x8 kf[4][2];
#pragma unroll
    for (int nt = 0; nt < 4; nt++)
#pragma unroll
      for (int kh = 0; kh < 2; kh++)
        kf[nt][kh] = *(const bf16x8*)(kbase + (size_t)(kv0 + nt * 16 + lr) * 64 + kh * 32 + quad * 8);

    f32x4 st[2][4];
#pragma unroll
    for (int qt = 0; qt < 2; qt++)
#pragma unroll
      for (int nt = 0; nt < 4; nt++) {
        f32x4 z = {};
        z = __builtin_amdgcn_mfma_f32_16x16x32_bf16(kf[nt][0], qf[qt][0], z, 0, 0, 0);
        z = __builtin_amdgcn_mfma_f32_16x16x32_bf16(kf[nt][1], qf[qt][1], z, 0, 0, 0);
        st[qt][nt] = z;
      }

    bf16x8 vf[4][2];
#pragma unroll
    for (int nt2 = 0; nt2 < 4; nt2++)
#pragma unroll
      for (int kt = 0; kt < 2; kt++)
        vf[nt2][kt] = *(const bf16x8*)(vbase + (size_t)(nt2 * 16 + lr) * NPAD + kv0 + kt * 32 + quad * 8);

#pragma unroll
    for (int qt = 0; qt < 2; qt++) {
      float rs = 0.0f;
#pragma unroll
      for (int nt = 0; nt < 4; nt++) {
        f32x4 pv;
#pragma unroll
        for (int r = 0; r < 4; r++) {
          float p = __builtin_amdgcn_exp2f(st[qt][nt][r] * C1 + C0);
          if (masked && !(nt == 0 && quad == 0 && r == 0)) p = 0.0f;
          pv[r] = p;
        }
        rs += pv[0] + pv[1] + pv[2] + pv[3];
        bf16x4 pk = {(__bf16)pv[0], (__bf16)pv[1], (__bf16)pv[2], (__bf16)pv[3]};
        *(bf16x4*)&pw[qt * 1152 + lr * 72 + nt * 16 + quad * 4] = pk;
      }
      l_p[qt] += rs;
    }

    bf16x8 pf[2][2];
#pragma unroll
    for (int qt = 0; qt < 2; qt++)
#pragma unroll
      for (int kt = 0; kt < 2; kt++)
        pf[qt][kt] = *(const bf16x8*)&pw[qt * 1152 + lr * 72 + kt * 32 + quad * 8];

#pragma unroll
    for (int qt = 0; qt < 2; qt++)
#pragma unroll
      for (int nt2 = 0; nt2 < 4; nt2++) {
        O[qt][nt2] = __builtin_amdgcn_mfma_f32_16x16x32_bf16(vf[nt2][0], pf[qt][0], O[qt][nt2], 0, 0, 0);
        O[qt][nt2] = __builtin_amdgcn_mfma_f32_16x16x32_bf16(vf[nt2][1], pf[qt][1], O[qt][nt2], 0, 0, 0);
      }
  };

  // this wave's half of the kv range (tile 9 = kv0 576 is the masked tail)
#pragma unroll 1
  for (int it = half * 5; it < half * 5 + 5; it++) tile(it * 64, it == 9);

  // ---- cross-half combine: O,l are pure sums (fixed-max softmax) ----
  __syncthreads();                       // all waves done with P slabs
  float* comb = &Xf[0][0];
  if (half == 1) {
    float* cb = comb + qs * 2176;        // 2048 O + 128 l per qslice
#pragma unroll
    for (int qt = 0; qt < 2; qt++) {
#pragma unroll
      for (int nt2 = 0; nt2 < 4; nt2++)
        *(f32x4*)&cb[qt * 1024 + nt2 * 256 + lane * 4] = O[qt][nt2];
      cb[2048 + qt * 64 + lane] = l_p[qt];
    }
  }
  __syncthreads();
  if (half == 0) {
    const float* cb = comb + qs * 2176;
#pragma unroll
    for (int qt = 0; qt < 2; qt++) {
#pragma unroll
      for (int nt2 = 0; nt2 < 4; nt2++) {
        f32x4 t = *(const f32x4*)&cb[qt * 1024 + nt2 * 256 + lane * 4];
#pragma unroll
        for (int r = 0; r < 4; r++) O[qt][nt2][r] += t[r];
      }
      l_p[qt] += cb[2048 + qt * 64 + lane];
    }
  }
  __syncthreads();                       // combine data dead; slabs reusable
  if (half == 1) return;

  // ---- epilogue (waves 0-3, unchanged) ----
#pragma unroll
  for (int qt = 0; qt < 2; qt++) {
    float lf = l_p[qt];
    lf += __shfl_xor(lf, 16, 64);
    lf += __shfl_xor(lf, 32, 64);
    float inv = 1.0f / lf;
#pragma unroll
    for (int nt2 = 0; nt2 < 4; nt2++) {
      f32x4 t;
#pragma unroll
      for (int r = 0; r < 4; r++) t[r] = O[qt][nt2][r] * inv;
      *(f32x4*)&xw[lr * 68 + nt2 * 16 + quad * 4] = t;
    }
#pragma unroll
    for (int p = 0; p < 4; p++) {
      int lm = p * 4 + quad;
      int s = qbase + qt * 16 + lm;
      if (s < NSEQ) {
        f32x4 t = *(const f32x4*)&xw[lm * 68 + lr * 4];
        bf16x4 hi;
#pragma unroll
        for (int r = 0; r < 4; r++) hi[r] = (__bf16)t[r];
        size_t base = ((size_t)b * NSEQ + s) * CDIM + h * 64 + lr * 4;
        *(bf16x4*)&aoh[base] = hi;
      }
    }
  }
}

// ---------------- GEMM2: attn_out @ w_proj^T + bias (plain bf16) -----------

#define G2_NWG (6 * 145)

__launch_bounds__(256, 2)
__global__ void gemm2(const __bf16* __restrict__ A, const __bf16* __restrict__ Bw,
                      const float* __restrict__ bias, float* __restrict__ out) {
  __shared__ __bf16 As[3][128 * 32];
  __shared__ __bf16 Bs[3][128 * 32];
  const int wgid = xcd_swizzle(blockIdx.x, G2_NWG);
  const int bn = wgid % 6, bm = wgid / 6;
  const int tid = threadIdx.x;
  const int w = tid >> 6, lane = tid & 63;
  const int lr = lane & 15, quad = lane >> 4;
  const int r0 = tid >> 2;
  const int kq = (tid & 3) * 8;
  const int K = CDIM;

  f32x4 acc[4][4] = {};
  const __bf16* Ab = A + (size_t)(bm * 128 + r0) * K + kq;
  const __bf16* Bb = Bw + (size_t)(bn * 128 + r0) * K + kq;
  const int wm = (w >> 1) * 64, wn = (w & 1) * 64;

  auto stage = [&](int kt, int buf) __attribute__((always_inline)) {
    gload16(Ab + kt, &As[buf][tid * 8]);
    gload16(Ab + kt + 64 * K, &As[buf][tid * 8 + 2048]);
    gload16(Bb + kt, &Bs[buf][tid * 8]);
    gload16(Bb + kt + 64 * K, &Bs[buf][tid * 8 + 2048]);
  };

  stage(0, 0);
  stage(32, 1);
  asm volatile("s_waitcnt vmcnt(4)" ::: "memory");
  asm volatile("s_barrier" ::: "memory");

  int c0 = 0, c1 = 1, c2 = 2;
#pragma unroll 1
  for (int kt = 0; kt < K; kt += 32) {
    if (kt + 64 < K) stage(kt + 64, c2);

    bf16x8 af[4], bfr[4];
#pragma unroll
    for (int i = 0; i < 4; i++) {
      af[i]  = *(const bf16x8*)&As[c0][(wm + i * 16 + lr) * 32 + quad * 8];
      bfr[i] = *(const bf16x8*)&Bs[c0][(wn + i * 16 + lr) * 32 + quad * 8];
    }
#pragma unroll
    for (int i = 0; i < 4; i++)
#pragma unroll
      for (int j = 0; j < 4; j++)
        acc[i][j] = __builtin_amdgcn_mfma_f32_16x16x32_bf16(af[i], bfr[j], acc[i][j], 0, 0, 0);

    if (kt + 64 < K)      asm volatile("s_waitcnt vmcnt(4)" ::: "memory");
    else if (kt + 32 < K) asm volatile("s_waitcnt vmcnt(0)" ::: "memory");
    asm volatile("s_barrier" ::: "memory");

    int tmp = c0; c0 = c1; c1 = c2; c2 = tmp;
  }

#pragma unroll
  for (int i = 0; i < 4; i++)
#pragma unroll
    for (int r = 0; r < 4; r++) {
      int m = bm * 128 + wm + i * 16 + quad * 4 + r;
      if (m < M_ROWS) {
#pragma unroll
        for (int j = 0; j < 4; j++) {
          int n = bn * 128 + wn + j * 16 + lr;
          out[(size_t)m * CDIM + n] = acc[i][j][r] + bias[n];
        }
      }
    }
}

// ------------------------------ launcher -----------------------------------

extern "C" void kernel_launch(void* const* d_in, const int* in_sizes, int n_in,
                              void* d_out, int out_size, void* d_ws, size_t ws_size,
                              hipStream_t stream) {
  const float* x      = (const float*)d_in[0];
  const float* w_qkv  = (const float*)d_in[1];
  const float* w_proj = (const float*)d_in[2];
  const float* b_proj = (const float*)d_in[3];
  const float* cosp   = (const float*)d_in[4];
  const float* sinp   = (const float*)d_in[5];
  float* out = (float*)d_out;

  char* ws = (char*)d_ws;
  auto carve = [&](size_t elts) {
    __bf16* p = (__bf16*)ws;
    ws += ((elts * 2 + 255) / 256) * 256;
    return p;
  };
  __bf16* xb    = carve((size_t)M_PAD * CDIM);
  __bf16* wqkvb = carve((size_t)QKVN * CDIM);
  __bf16* wpb   = carve((size_t)CDIM * CDIM);
  __bf16* qq    = carve((size_t)BHEADS * NPAD * 64);
  __bf16* kk    = carve((size_t)BHEADS * NPAD * 64);
  __bf16* vv    = carve((size_t)BHEADS * NPAD * 64);   // vT for attn
  __bf16* aoh   = carve((size_t)M_PAD * CDIM);
  // vr (row-major V) aliases aoh: written by gemm1, consumed by vtrans
  // BEFORE attn writes aoh.
  __bf16* vr    = aoh;

  cvt_pad<<<((M_PAD * CDIM) / 4 + 255) / 256, 256, 0, stream>>>(x, xb, (long)M_ROWS * CDIM, (long)M_PAD * CDIM);
  cvt_pad<<<((QKVN * CDIM) / 4 + 255) / 256, 256, 0, stream>>>(w_qkv, wqkvb, (long)QKVN * CDIM, (long)QKVN * CDIM);
  cvt_pad<<<((CDIM * CDIM) / 4 + 255) / 256, 256, 0, stream>>>(w_proj, wpb, (long)CDIM * CDIM, (long)CDIM * CDIM);
  pad_zero<<<(BHEADS * 63 * 64 + 255) / 256, 256, 0, stream>>>(qq, kk);
  gemm1<<<G1_NWG, 256, 0, stream>>>(xb, wqkvb, qq, kk, vr, cosp, sinp);
  vtrans<<<BHEADS * 10, 256, 0, stream>>>(vr, vv);
  attn<<<AT_NWG, 512, 0, stream>>>(qq, kk, vv, aoh);
  gemm2<<<G2_NWG, 256, 0, stream>>>(aoh, wpb, b_proj, out);
}

// Round 6
// 428.652 us; speedup vs baseline: 1.1212x; 1.1212x over previous
//
#include <hip/hip_runtime.h>

// ---------------------------------------------------------------------------
// Attention (B=32,N=577,C=768,H=12,D=64) with RoPE, fp32 I/O, bf16 MFMA core.
// R14: revert attn to R12 structure (R13's 512-thread split-KV spilled:
// WRITE_SIZE 27.7->118MB = scratch traffic, MfmaUtil down). Three chain cuts
// on the R12 base: (1) kf prefetch-in-place — issue next tile's K loads into
// the dead kf regs right after QK, hiding load latency under softmax+PV,
// zero extra VGPRs; (2) last tile (kv0=576) has ONE valid column -> replaced
// by a VALU dot-product path (saves a full 64-wide tile); (3) s_setprio(1)
// around QK/PV MFMA clusters (attn-only per m190/m191).
// gemm1/gemm2/vtrans/cvt unchanged from R12.
// ---------------------------------------------------------------------------

#define M_ROWS 18464          // B*N
#define M_PAD  18560          // 145*128
#define CDIM   768
#define QKVN   2304
#define NHEADS 12
#define BHEADS 384            // B*H
#define NSEQ   577
#define NPAD   640            // 10*64
#define SCALE  0.125f

typedef __bf16 bf16x8 __attribute__((ext_vector_type(8)));
typedef __bf16 bf16x4 __attribute__((ext_vector_type(4)));
typedef float  f32x4  __attribute__((ext_vector_type(4)));

typedef const __attribute__((address_space(1))) void* gas_ptr;
typedef __attribute__((address_space(3))) void* las_ptr;

__device__ inline void gload16(const __bf16* g, __bf16* l) {
  __builtin_amdgcn_global_load_lds((gas_ptr)g, (las_ptr)l, 16, 0, 0);
}

// m204 bijective chunked XCD swizzle
__device__ inline int xcd_swizzle(int orig, int nwg) {
  int q = nwg >> 3, r = nwg & 7;
  int xcd = orig & 7, idx = orig >> 3;
  int base = (xcd < r) ? xcd * (q + 1) : r * (q + 1) + (xcd - r) * q;
  return base + idx;
}

// ------------------------- converts / padding ------------------------------

__global__ void cvt_pad(const float* __restrict__ src, __bf16* __restrict__ dst,
                        long n_src, long n_dst) {
  long i = ((long)blockIdx.x * 256 + threadIdx.x) * 4;
  if (i >= n_dst) return;
  if (i + 3 < n_src) {
    f32x4 v = *(const f32x4*)(src + i);
    bf16x4 o = {(__bf16)v[0], (__bf16)v[1], (__bf16)v[2], (__bf16)v[3]};
    *(bf16x4*)(dst + i) = o;
  } else {
#pragma unroll
    for (int j = 0; j < 4; j++)
      if (i + j < n_dst) dst[i + j] = (i + j < n_src) ? (__bf16)src[i + j] : (__bf16)0.0f;
  }
}

// zero the seq-padding region (s in [577,640)) of q, k
__global__ void pad_zero(__bf16* __restrict__ q, __bf16* __restrict__ k) {
  int i = blockIdx.x * 256 + threadIdx.x;
  if (i >= BHEADS * 63 * 64) return;
  int d = i & 63;
  int t = i >> 6;
  int sp = t % 63, bh = t / 63;
  int s = NSEQ + sp;
  q[((size_t)bh * NPAD + s) * 64 + d] = (__bf16)0.0f;
  k[((size_t)bh * NPAD + s) * 64 + d] = (__bf16)0.0f;
}

// ------------------------- GEMM1: x @ w_qkv^T + RoPE -----------------------
// K-loop: 3-buffer 2-deep prefetch, counted vmcnt(4), raw barriers.
// Epilogue: phase A = f32 RoPE -> LDS tile [128][136]; phase B = coalesced
// bf16x8 stores. V stored ROW-major into vr.

#define G1_NWG (18 * 145)

__launch_bounds__(256, 2)
__global__ void gemm1(const __bf16* __restrict__ A, const __bf16* __restrict__ Bw,
                      __bf16* __restrict__ qq, __bf16* __restrict__ kk,
                      __bf16* __restrict__ vr,
                      const float* __restrict__ cs, const float* __restrict__ sn) {
  __shared__ __bf16 smem[3 * 4096 * 2];   // As[3] | Bs[3], reused as out-tile
  const int wgid = xcd_swizzle(blockIdx.x, G1_NWG);
  const int bn = wgid % 18, bm = wgid / 18;
  const int tid = threadIdx.x;
  const int w = tid >> 6, lane = tid & 63;
  const int lr = lane & 15, quad = lane >> 4;
  const int r0 = tid >> 2;
  const int kq = (tid & 3) * 8;
  const int K = CDIM;

  f32x4 acc[4][4] = {};
  const __bf16* Ab = A + (size_t)(bm * 128 + r0) * K + kq;
  const __bf16* Bb = Bw + (size_t)(bn * 128 + r0) * K + kq;
  const int wm = (w >> 1) * 64, wn = (w & 1) * 64;

  auto stage = [&](int kt, int buf) __attribute__((always_inline)) {
    gload16(Ab + kt, &smem[buf * 4096 + tid * 8]);
    gload16(Ab + kt + 64 * K, &smem[buf * 4096 + tid * 8 + 2048]);
    gload16(Bb + kt, &smem[12288 + buf * 4096 + tid * 8]);
    gload16(Bb + kt + 64 * K, &smem[12288 + buf * 4096 + tid * 8 + 2048]);
  };

  stage(0, 0);
  stage(32, 1);
  asm volatile("s_waitcnt vmcnt(4)" ::: "memory");
  asm volatile("s_barrier" ::: "memory");

  int c0 = 0, c1 = 1, c2 = 2;
#pragma unroll 1
  for (int kt = 0; kt < K; kt += 32) {
    if (kt + 64 < K) stage(kt + 64, c2);

    bf16x8 af[4], bfr[4];
#pragma unroll
    for (int i = 0; i < 4; i++) {
      af[i]  = *(const bf16x8*)&smem[c0 * 4096 + (wm + i * 16 + lr) * 32 + quad * 8];
      bfr[i] = *(const bf16x8*)&smem[12288 + c0 * 4096 + (wn + i * 16 + lr) * 32 + quad * 8];
    }
#pragma unroll
    for (int i = 0; i < 4; i++)
#pragma unroll
      for (int j = 0; j < 4; j++)
        acc[i][j] = __builtin_amdgcn_mfma_f32_16x16x32_bf16(af[i], bfr[j], acc[i][j], 0, 0, 0);

    if (kt + 64 < K)      asm volatile("s_waitcnt vmcnt(4)" ::: "memory");
    else if (kt + 32 < K) asm volatile("s_waitcnt vmcnt(0)" ::: "memory");
    asm volatile("s_barrier" ::: "memory");

    int tmp = c0; c0 = c1; c1 = c2; c2 = tmp;
  }

  // ---------------- epilogue: LDS bounce ----------------
  __syncthreads();
  __bf16* tile = smem;                // [128][136] bf16
  const bool isv = (bn >= 12);

#pragma unroll
  for (int i = 0; i < 4; i++) {
#pragma unroll
    for (int r = 0; r < 4; r++) {
      int ml = wm + i * 16 + quad * 4 + r;
      int m = bm * 128 + ml;
      int s = 0;
      if (!isv) { int b = m / NSEQ; s = m - b * NSEQ; }
#pragma unroll
      for (int j = 0; j < 4; j++) {
        int nl = wn + j * 16 + lr;
        float v = acc[i][j][r];
        float outv = v;
        if (!isv) {
          float pv = __shfl_xor(v, 1, 64);
          if (s >= 1 && m < M_ROWS) {
            int d = nl & 63;
            float c  = cs[(size_t)(s - 1) * 32 + (d >> 1)];
            float sv = sn[(size_t)(s - 1) * 32 + (d >> 1)];
            outv = (nl & 1) ? (pv * sv + v * c) : (v * c - pv * sv);
          }
        }
        tile[ml * 136 + nl] = (__bf16)outv;
      }
    }
  }
  __syncthreads();

  {
    const int tq = tid >> 4, tc = tid & 15;
    const int t_blk = bn / 6;             // 0=q 1=k 2=v
    const int bnq = bn % 6;
    __bf16* dstb = (t_blk == 0) ? qq : (t_blk == 1) ? kk : vr;
    const int SS = (t_blk == 2) ? NSEQ : NPAD;
    const int h = bnq * 2 + (tc >> 3);
    const int d0 = (tc & 7) * 8;
#pragma unroll
    for (int p = 0; p < 8; p++) {
      int ml = p * 16 + tq;
      int m = bm * 128 + ml;
      if (m < M_ROWS) {
        int b = m / NSEQ, s = m - b * NSEQ;
        bf16x8 val = *(const bf16x8*)&tile[ml * 136 + tc * 8];
        *(bf16x8*)&dstb[(((size_t)(b * NHEADS + h) * SS + s) << 6) + d0] = val;
      }
    }
  }
}

// -------- vtrans: vr [bh][s<577][d] -> vT [bh][d][s_pad 640] (zero pad) ----

__global__ void vtrans(const __bf16* __restrict__ vr, __bf16* __restrict__ vt) {
  __shared__ __bf16 t[64 * 72];
  int blk = blockIdx.x;
  int bh = blk / 10, sc = blk % 10;
  int tid = threadIdx.x;
  int ts = tid >> 2;
  int dc = (tid & 3) * 16;
  int s = sc * 64 + ts;
  bf16x8 a = {}, b2 = {};
  if (s < NSEQ) {
    const __bf16* src = vr + ((size_t)bh * NSEQ + s) * 64 + dc;
    a  = *(const bf16x8*)src;
    b2 = *(const bf16x8*)(src + 8);
  }
#pragma unroll
  for (int e = 0; e < 8; e++) {
    t[(dc + e) * 72 + ts]     = a[e];
    t[(dc + 8 + e) * 72 + ts] = b2[e];
  }
  __syncthreads();
  int d = tid >> 2;
  int scol = (tid & 3) * 16;
  bf16x8 o0 = *(const bf16x8*)&t[d * 72 + scol];
  bf16x8 o1 = *(const bf16x8*)&t[d * 72 + scol + 8];
  __bf16* dst = vt + ((size_t)bh * 64 + d) * NPAD + sc * 64 + scol;
  *(bf16x8*)dst = o0;
  *(bf16x8*)(dst + 8) = o1;
}

// --------------------- flash attention (fixed-max) -------------------------
// R12 base + R14 deltas: kf prefetch-in-place, setprio around MFMA clusters,
// VALU tail for kv=576 (the only valid column of the last tile).

#define AT_NWG (BHEADS * 5)

__launch_bounds__(256, 3)
__global__ void attn(const __bf16* __restrict__ q, const __bf16* __restrict__ k,
                     const __bf16* __restrict__ vT, __bf16* __restrict__ aoh) {
  __shared__ float Xf[4][1152];
  const int blk = xcd_swizzle(blockIdx.x, AT_NWG);
  const int qt5 = blk % 5, bh = blk / 5;
  const int b = bh / NHEADS, h = bh % NHEADS;
  const int w = threadIdx.x >> 6, lane = threadIdx.x & 63;
  const int lr = lane & 15, quad = lane >> 4;
  const int qbase = qt5 * 128 + w * 32;

  float* xw = &Xf[w][0];
  __bf16* pw = (__bf16*)xw;

  // Q fragments (B-operand): B[n = q-col = lr][k = d = quad*8+j]
  bf16x8 qf[2][2];
#pragma unroll
  for (int qt = 0; qt < 2; qt++)
#pragma unroll
    for (int kh = 0; kh < 2; kh++)
      qf[qt][kh] = *(const bf16x8*)(q + ((size_t)bh * NPAD + qbase + qt * 16 + lr) * 64 + kh * 32 + quad * 8);

  f32x4 O[2][4] = {};
  float l_p[2] = {0.0f, 0.0f};
  const float C1 = SCALE * 1.44269504089f;
  const float C0 = -8.0f * 1.44269504089f;
  const __bf16* kbase = k + (size_t)bh * NPAD * 64;
  const __bf16* vbase = vT + (size_t)bh * 64 * NPAD;

  // K fragments (A-operand): A[m = kv = lr][k = d]
  bf16x8 kf[4][2];
  auto loadK = [&](int kv0) __attribute__((always_inline)) {
#pragma unroll
    for (int nt = 0; nt < 4; nt++)
#pragma unroll
      for (int kh = 0; kh < 2; kh++)
        kf[nt][kh] = *(const bf16x8*)(kbase + (size_t)(kv0 + nt * 16 + lr) * 64 + kh * 32 + quad * 8);
  };

  loadK(0);
#pragma unroll 1
  for (int it = 0; it < 9; it++) {
    const int kv0 = it * 64;

    f32x4 st[2][4];
    __builtin_amdgcn_s_setprio(1);
#pragma unroll
    for (int qt = 0; qt < 2; qt++)
#pragma unroll
      for (int nt = 0; nt < 4; nt++) {
        f32x4 z = {};
        z = __builtin_amdgcn_mfma_f32_16x16x32_bf16(kf[nt][0], qf[qt][0], z, 0, 0, 0);
        z = __builtin_amdgcn_mfma_f32_16x16x32_bf16(kf[nt][1], qf[qt][1], z, 0, 0, 0);
        st[qt][nt] = z;
      }
    __builtin_amdgcn_s_setprio(0);

    // V^T fragments for this tile (A-operand, needed by PV) — issue first.
    bf16x8 vf[4][2];
#pragma unroll
    for (int nt2 = 0; nt2 < 4; nt2++)
#pragma unroll
      for (int kt = 0; kt < 2; kt++)
        vf[nt2][kt] = *(const bf16x8*)(vbase + (size_t)(nt2 * 16 + lr) * NPAD + kv0 + kt * 32 + quad * 8);

    // prefetch next tile's K into the now-dead kf regs (WAR after QK);
    // latency hides under softmax + PV.
    if (it < 8) loadK(kv0 + 64);

#pragma unroll
    for (int qt = 0; qt < 2; qt++) {
      float rs = 0.0f;
#pragma unroll
      for (int nt = 0; nt < 4; nt++) {
        f32x4 pv;
#pragma unroll
        for (int r = 0; r < 4; r++)
          pv[r] = __builtin_amdgcn_exp2f(st[qt][nt][r] * C1 + C0);
        rs += pv[0] + pv[1] + pv[2] + pv[3];
        bf16x4 pk = {(__bf16)pv[0], (__bf16)pv[1], (__bf16)pv[2], (__bf16)pv[3]};
        *(bf16x4*)&pw[qt * 1152 + lr * 72 + nt * 16 + quad * 4] = pk;
      }
      l_p[qt] += rs;
    }

    // P^T fragments (B-operand): B[n = q-col = lr][k = kv = quad*8+j]
    bf16x8 pf[2][2];
#pragma unroll
    for (int qt = 0; qt < 2; qt++)
#pragma unroll
      for (int kt = 0; kt < 2; kt++)
        pf[qt][kt] = *(const bf16x8*)&pw[qt * 1152 + lr * 72 + kt * 32 + quad * 8];

    __builtin_amdgcn_s_setprio(1);
#pragma unroll
    for (int qt = 0; qt < 2; qt++)
#pragma unroll
      for (int nt2 = 0; nt2 < 4; nt2++) {
        O[qt][nt2] = __builtin_amdgcn_mfma_f32_16x16x32_bf16(vf[nt2][0], pf[qt][0], O[qt][nt2], 0, 0, 0);
        O[qt][nt2] = __builtin_amdgcn_mfma_f32_16x16x32_bf16(vf[nt2][1], pf[qt][1], O[qt][nt2], 0, 0, 0);
      }
    __builtin_amdgcn_s_setprio(0);
  }

  // ---- kv = 576 tail: the last tile's ONLY valid column -> VALU path ----
  {
    bf16x8 k5[2];
#pragma unroll
    for (int kh = 0; kh < 2; kh++)
      k5[kh] = *(const bf16x8*)(kbase + (size_t)576 * 64 + kh * 32 + quad * 8);
    float p5[2];
#pragma unroll
    for (int qt = 0; qt < 2; qt++) {
      float s = 0.0f;
#pragma unroll
      for (int kh = 0; kh < 2; kh++)
#pragma unroll
        for (int j = 0; j < 8; j++)
          s += (float)qf[qt][kh][j] * (float)k5[kh][j];
      s += __shfl_xor(s, 16, 64);       // sum across quads -> full dot(q,k576)
      s += __shfl_xor(s, 32, 64);
      p5[qt] = __builtin_amdgcn_exp2f(s * C1 + C0);
      if (quad == 0) l_p[qt] += p5[qt]; // epilogue reduces over quads: add once
    }
#pragma unroll
    for (int nt2 = 0; nt2 < 4; nt2++)
#pragma unroll
      for (int r = 0; r < 4; r++) {
        float vv = (float)vbase[(size_t)(nt2 * 16 + quad * 4 + r) * NPAD + 576];
        O[0][nt2][r] += p5[0] * vv;
        O[1][nt2][r] += p5[1] * vv;
      }
  }

  // ---- epilogue (unchanged) ----
#pragma unroll
  for (int qt = 0; qt < 2; qt++) {
    float lf = l_p[qt];
    lf += __shfl_xor(lf, 16, 64);
    lf += __shfl_xor(lf, 32, 64);
    float inv = 1.0f / lf;
#pragma unroll
    for (int nt2 = 0; nt2 < 4; nt2++) {
      f32x4 t;
#pragma unroll
      for (int r = 0; r < 4; r++) t[r] = O[qt][nt2][r] * inv;
      *(f32x4*)&xw[lr * 68 + nt2 * 16 + quad * 4] = t;
    }
#pragma unroll
    for (int p = 0; p < 4; p++) {
      int lm = p * 4 + quad;
      int s = qbase + qt * 16 + lm;
      if (s < NSEQ) {
        f32x4 t = *(const f32x4*)&xw[lm * 68 + lr * 4];
        bf16x4 hi;
#pragma unroll
        for (int r = 0; r < 4; r++) hi[r] = (__bf16)t[r];
        size_t base = ((size_t)b * NSEQ + s) * CDIM + h * 64 + lr * 4;
        *(bf16x4*)&aoh[base] = hi;
      }
    }
  }
}

// ---------------- GEMM2: attn_out @ w_proj^T + bias (plain bf16) -----------

#define G2_NWG (6 * 145)

__launch_bounds__(256, 2)
__global__ void gemm2(const __bf16* __restrict__ A, const __bf16* __restrict__ Bw,
                      const float* __restrict__ bias, float* __restrict__ out) {
  __shared__ __bf16 As[3][128 * 32];
  __shared__ __bf16 Bs[3][128 * 32];
  const int wgid = xcd_swizzle(blockIdx.x, G2_NWG);
  const int bn = wgid % 6, bm = wgid / 6;
  const int tid = threadIdx.x;
  const int w = tid >> 6, lane = tid & 63;
  const int lr = lane & 15, quad = lane >> 4;
  const int r0 = tid >> 2;
  const int kq = (tid & 3) * 8;
  const int K = CDIM;

  f32x4 acc[4][4] = {};
  const __bf16* Ab = A + (size_t)(bm * 128 + r0) * K + kq;
  const __bf16* Bb = Bw + (size_t)(bn * 128 + r0) * K + kq;
  const int wm = (w >> 1) * 64, wn = (w & 1) * 64;

  auto stage = [&](int kt, int buf) __attribute__((always_inline)) {
    gload16(Ab + kt, &As[buf][tid * 8]);
    gload16(Ab + kt + 64 * K, &As[buf][tid * 8 + 2048]);
    gload16(Bb + kt, &Bs[buf][tid * 8]);
    gload16(Bb + kt + 64 * K, &Bs[buf][tid * 8 + 2048]);
  };

  stage(0, 0);
  stage(32, 1);
  asm volatile("s_waitcnt vmcnt(4)" ::: "memory");
  asm volatile("s_barrier" ::: "memory");

  int c0 = 0, c1 = 1, c2 = 2;
#pragma unroll 1
  for (int kt = 0; kt < K; kt += 32) {
    if (kt + 64 < K) stage(kt + 64, c2);

    bf16x8 af[4], bfr[4];
#pragma unroll
    for (int i = 0; i < 4; i++) {
      af[i]  = *(const bf16x8*)&As[c0][(wm + i * 16 + lr) * 32 + quad * 8];
      bfr[i] = *(const bf16x8*)&Bs[c0][(wn + i * 16 + lr) * 32 + quad * 8];
    }
#pragma unroll
    for (int i = 0; i < 4; i++)
#pragma unroll
      for (int j = 0; j < 4; j++)
        acc[i][j] = __builtin_amdgcn_mfma_f32_16x16x32_bf16(af[i], bfr[j], acc[i][j], 0, 0, 0);

    if (kt + 64 < K)      asm volatile("s_waitcnt vmcnt(4)" ::: "memory");
    else if (kt + 32 < K) asm volatile("s_waitcnt vmcnt(0)" ::: "memory");
    asm volatile("s_barrier" ::: "memory");

    int tmp = c0; c0 = c1; c1 = c2; c2 = tmp;
  }

#pragma unroll
  for (int i = 0; i < 4; i++)
#pragma unroll
    for (int r = 0; r < 4; r++) {
      int m = bm * 128 + wm + i * 16 + quad * 4 + r;
      if (m < M_ROWS) {
#pragma unroll
        for (int j = 0; j < 4; j++) {
          int n = bn * 128 + wn + j * 16 + lr;
          out[(size_t)m * CDIM + n] = acc[i][j][r] + bias[n];
        }
      }
    }
}

// ------------------------------ launcher -----------------------------------

extern "C" void kernel_launch(void* const* d_in, const int* in_sizes, int n_in,
                              void* d_out, int out_size, void* d_ws, size_t ws_size,
                              hipStream_t stream) {
  const float* x      = (const float*)d_in[0];
  const float* w_qkv  = (const float*)d_in[1];
  const float* w_proj = (const float*)d_in[2];
  const float* b_proj = (const float*)d_in[3];
  const float* cosp   = (const float*)d_in[4];
  const float* sinp   = (const float*)d_in[5];
  float* out = (float*)d_out;

  char* ws = (char*)d_ws;
  auto carve = [&](size_t elts) {
    __bf16* p = (__bf16*)ws;
    ws += ((elts * 2 + 255) / 256) * 256;
    return p;
  };
  __bf16* xb    = carve((size_t)M_PAD * CDIM);
  __bf16* wqkvb = carve((size_t)QKVN * CDIM);
  __bf16* wpb   = carve((size_t)CDIM * CDIM);
  __bf16* qq    = carve((size_t)BHEADS * NPAD * 64);
  __bf16* kk    = carve((size_t)BHEADS * NPAD * 64);
  __bf16* vv    = carve((size_t)BHEADS * NPAD * 64);   // vT for attn
  __bf16* aoh   = carve((size_t)M_PAD * CDIM);
  // vr (row-major V) aliases aoh: written by gemm1, consumed by vtrans
  // BEFORE attn writes aoh.
  __bf16* vr    = aoh;

  cvt_pad<<<((M_PAD * CDIM) / 4 + 255) / 256, 256, 0, stream>>>(x, xb, (long)M_ROWS * CDIM, (long)M_PAD * CDIM);
  cvt_pad<<<((QKVN * CDIM) / 4 + 255) / 256, 256, 0, stream>>>(w_qkv, wqkvb, (long)QKVN * CDIM, (long)QKVN * CDIM);
  cvt_pad<<<((CDIM * CDIM) / 4 + 255) / 256, 256, 0, stream>>>(w_proj, wpb, (long)CDIM * CDIM, (long)CDIM * CDIM);
  pad_zero<<<(BHEADS * 63 * 64 + 255) / 256, 256, 0, stream>>>(qq, kk);
  gemm1<<<G1_NWG, 256, 0, stream>>>(xb, wqkvb, qq, kk, vr, cosp, sinp);
  vtrans<<<BHEADS * 10, 256, 0, stream>>>(vr, vv);
  attn<<<AT_NWG, 256, 0, stream>>>(qq, kk, vv, aoh);
  gemm2<<<G2_NWG, 256, 0, stream>>>(aoh, wpb, b_proj, out);
}

// Round 7
// 355.636 us; speedup vs baseline: 1.3514x; 1.2053x over previous
//
#include <hip/hip_runtime.h>

// ---------------------------------------------------------------------------
// Attention (B=32,N=577,C=768,H=12,D=64) with RoPE, fp32 I/O, bf16 MFMA core.
// R15: attn K/V LDS staging. Diagnosis: all 4 waves of a block were loading
// IDENTICAL K,V fragments from global (4x redundant issue + per-wave global
// latency on the chain => 10.7k cyc/tile vs 1.5k work, MfmaUtil 10%). Fix:
// stage K[64][64]+V[64][64] per kv-tile in LDS once per block via
// global_load_lds, double-buffered, prefetch-at-top + vmcnt(0)+barrier at
// bottom (drain free: ~3k cyc compute in between). chunk^=(row&7) XOR swizzle
// applied on BOTH sides (pre-swizzled global source, rule #21) to avoid
// 16-way bank conflicts on the kf/vf ds_read_b128. Tiles 0..8 touch only
// kv<=575; kv=576 stays on R14's VALU tail. setprio kept.
// gemm1/gemm2/vtrans/cvt unchanged from R14.
// ---------------------------------------------------------------------------

#define M_ROWS 18464          // B*N
#define M_PAD  18560          // 145*128
#define CDIM   768
#define QKVN   2304
#define NHEADS 12
#define BHEADS 384            // B*H
#define NSEQ   577
#define NPAD   640            // 10*64
#define SCALE  0.125f

typedef __bf16 bf16x8 __attribute__((ext_vector_type(8)));
typedef __bf16 bf16x4 __attribute__((ext_vector_type(4)));
typedef float  f32x4  __attribute__((ext_vector_type(4)));

typedef const __attribute__((address_space(1))) void* gas_ptr;
typedef __attribute__((address_space(3))) void* las_ptr;

__device__ inline void gload16(const __bf16* g, __bf16* l) {
  __builtin_amdgcn_global_load_lds((gas_ptr)g, (las_ptr)l, 16, 0, 0);
}

// m204 bijective chunked XCD swizzle
__device__ inline int xcd_swizzle(int orig, int nwg) {
  int q = nwg >> 3, r = nwg & 7;
  int xcd = orig & 7, idx = orig >> 3;
  int base = (xcd < r) ? xcd * (q + 1) : r * (q + 1) + (xcd - r) * q;
  return base + idx;
}

// ------------------------- converts / padding ------------------------------

__global__ void cvt_pad(const float* __restrict__ src, __bf16* __restrict__ dst,
                        long n_src, long n_dst) {
  long i = ((long)blockIdx.x * 256 + threadIdx.x) * 4;
  if (i >= n_dst) return;
  if (i + 3 < n_src) {
    f32x4 v = *(const f32x4*)(src + i);
    bf16x4 o = {(__bf16)v[0], (__bf16)v[1], (__bf16)v[2], (__bf16)v[3]};
    *(bf16x4*)(dst + i) = o;
  } else {
#pragma unroll
    for (int j = 0; j < 4; j++)
      if (i + j < n_dst) dst[i + j] = (i + j < n_src) ? (__bf16)src[i + j] : (__bf16)0.0f;
  }
}

// zero the seq-padding region (s in [577,640)) of q, k
__global__ void pad_zero(__bf16* __restrict__ q, __bf16* __restrict__ k) {
  int i = blockIdx.x * 256 + threadIdx.x;
  if (i >= BHEADS * 63 * 64) return;
  int d = i & 63;
  int t = i >> 6;
  int sp = t % 63, bh = t / 63;
  int s = NSEQ + sp;
  q[((size_t)bh * NPAD + s) * 64 + d] = (__bf16)0.0f;
  k[((size_t)bh * NPAD + s) * 64 + d] = (__bf16)0.0f;
}

// ------------------------- GEMM1: x @ w_qkv^T + RoPE -----------------------
// K-loop: 3-buffer 2-deep prefetch, counted vmcnt(4), raw barriers.
// Epilogue: phase A = f32 RoPE -> LDS tile [128][136]; phase B = coalesced
// bf16x8 stores. V stored ROW-major into vr.

#define G1_NWG (18 * 145)

__launch_bounds__(256, 2)
__global__ void gemm1(const __bf16* __restrict__ A, const __bf16* __restrict__ Bw,
                      __bf16* __restrict__ qq, __bf16* __restrict__ kk,
                      __bf16* __restrict__ vr,
                      const float* __restrict__ cs, const float* __restrict__ sn) {
  __shared__ __bf16 smem[3 * 4096 * 2];   // As[3] | Bs[3], reused as out-tile
  const int wgid = xcd_swizzle(blockIdx.x, G1_NWG);
  const int bn = wgid % 18, bm = wgid / 18;
  const int tid = threadIdx.x;
  const int w = tid >> 6, lane = tid & 63;
  const int lr = lane & 15, quad = lane >> 4;
  const int r0 = tid >> 2;
  const int kq = (tid & 3) * 8;
  const int K = CDIM;

  f32x4 acc[4][4] = {};
  const __bf16* Ab = A + (size_t)(bm * 128 + r0) * K + kq;
  const __bf16* Bb = Bw + (size_t)(bn * 128 + r0) * K + kq;
  const int wm = (w >> 1) * 64, wn = (w & 1) * 64;

  auto stage = [&](int kt, int buf) __attribute__((always_inline)) {
    gload16(Ab + kt, &smem[buf * 4096 + tid * 8]);
    gload16(Ab + kt + 64 * K, &smem[buf * 4096 + tid * 8 + 2048]);
    gload16(Bb + kt, &smem[12288 + buf * 4096 + tid * 8]);
    gload16(Bb + kt + 64 * K, &smem[12288 + buf * 4096 + tid * 8 + 2048]);
  };

  stage(0, 0);
  stage(32, 1);
  asm volatile("s_waitcnt vmcnt(4)" ::: "memory");
  asm volatile("s_barrier" ::: "memory");

  int c0 = 0, c1 = 1, c2 = 2;
#pragma unroll 1
  for (int kt = 0; kt < K; kt += 32) {
    if (kt + 64 < K) stage(kt + 64, c2);

    bf16x8 af[4], bfr[4];
#pragma unroll
    for (int i = 0; i < 4; i++) {
      af[i]  = *(const bf16x8*)&smem[c0 * 4096 + (wm + i * 16 + lr) * 32 + quad * 8];
      bfr[i] = *(const bf16x8*)&smem[12288 + c0 * 4096 + (wn + i * 16 + lr) * 32 + quad * 8];
    }
#pragma unroll
    for (int i = 0; i < 4; i++)
#pragma unroll
      for (int j = 0; j < 4; j++)
        acc[i][j] = __builtin_amdgcn_mfma_f32_16x16x32_bf16(af[i], bfr[j], acc[i][j], 0, 0, 0);

    if (kt + 64 < K)      asm volatile("s_waitcnt vmcnt(4)" ::: "memory");
    else if (kt + 32 < K) asm volatile("s_waitcnt vmcnt(0)" ::: "memory");
    asm volatile("s_barrier" ::: "memory");

    int tmp = c0; c0 = c1; c1 = c2; c2 = tmp;
  }

  // ---------------- epilogue: LDS bounce ----------------
  __syncthreads();
  __bf16* tile = smem;                // [128][136] bf16
  const bool isv = (bn >= 12);

#pragma unroll
  for (int i = 0; i < 4; i++) {
#pragma unroll
    for (int r = 0; r < 4; r++) {
      int ml = wm + i * 16 + quad * 4 + r;
      int m = bm * 128 + ml;
      int s = 0;
      if (!isv) { int b = m / NSEQ; s = m - b * NSEQ; }
#pragma unroll
      for (int j = 0; j < 4; j++) {
        int nl = wn + j * 16 + lr;
        float v = acc[i][j][r];
        float outv = v;
        if (!isv) {
          float pv = __shfl_xor(v, 1, 64);
          if (s >= 1 && m < M_ROWS) {
            int d = nl & 63;
            float c  = cs[(size_t)(s - 1) * 32 + (d >> 1)];
            float sv = sn[(size_t)(s - 1) * 32 + (d >> 1)];
            outv = (nl & 1) ? (pv * sv + v * c) : (v * c - pv * sv);
          }
        }
        tile[ml * 136 + nl] = (__bf16)outv;
      }
    }
  }
  __syncthreads();

  {
    const int tq = tid >> 4, tc = tid & 15;
    const int t_blk = bn / 6;             // 0=q 1=k 2=v
    const int bnq = bn % 6;
    __bf16* dstb = (t_blk == 0) ? qq : (t_blk == 1) ? kk : vr;
    const int SS = (t_blk == 2) ? NSEQ : NPAD;
    const int h = bnq * 2 + (tc >> 3);
    const int d0 = (tc & 7) * 8;
#pragma unroll
    for (int p = 0; p < 8; p++) {
      int ml = p * 16 + tq;
      int m = bm * 128 + ml;
      if (m < M_ROWS) {
        int b = m / NSEQ, s = m - b * NSEQ;
        bf16x8 val = *(const bf16x8*)&tile[ml * 136 + tc * 8];
        *(bf16x8*)&dstb[(((size_t)(b * NHEADS + h) * SS + s) << 6) + d0] = val;
      }
    }
  }
}

// -------- vtrans: vr [bh][s<577][d] -> vT [bh][d][s_pad 640] (zero pad) ----

__global__ void vtrans(const __bf16* __restrict__ vr, __bf16* __restrict__ vt) {
  __shared__ __bf16 t[64 * 72];
  int blk = blockIdx.x;
  int bh = blk / 10, sc = blk % 10;
  int tid = threadIdx.x;
  int ts = tid >> 2;
  int dc = (tid & 3) * 16;
  int s = sc * 64 + ts;
  bf16x8 a = {}, b2 = {};
  if (s < NSEQ) {
    const __bf16* src = vr + ((size_t)bh * NSEQ + s) * 64 + dc;
    a  = *(const bf16x8*)src;
    b2 = *(const bf16x8*)(src + 8);
  }
#pragma unroll
  for (int e = 0; e < 8; e++) {
    t[(dc + e) * 72 + ts]     = a[e];
    t[(dc + 8 + e) * 72 + ts] = b2[e];
  }
  __syncthreads();
  int d = tid >> 2;
  int scol = (tid & 3) * 16;
  bf16x8 o0 = *(const bf16x8*)&t[d * 72 + scol];
  bf16x8 o1 = *(const bf16x8*)&t[d * 72 + scol + 8];
  __bf16* dst = vt + ((size_t)bh * 64 + d) * NPAD + sc * 64 + scol;
  *(bf16x8*)dst = o0;
  *(bf16x8*)(dst + 8) = o1;
}

// --------------------- flash attention (fixed-max) -------------------------
// R15: K/V LDS staging (shared by the 4 waves), double-buffered, XOR-swizzled.
// kv tiles 0..8 from LDS; kv=576 via VALU tail. Softmax/P path unchanged.

#define AT_NWG (BHEADS * 5)

__launch_bounds__(256, 3)
__global__ void attn(const __bf16* __restrict__ q, const __bf16* __restrict__ k,
                     const __bf16* __restrict__ vT, __bf16* __restrict__ aoh) {
  __shared__ __bf16 KVs[2][8192];        // per buf: K[64][64] | V^T[64][64]
  __shared__ float Xf[4][1152];          // per-wave P slabs / epilogue bounce
  const int blk = xcd_swizzle(blockIdx.x, AT_NWG);
  const int qt5 = blk % 5, bh = blk / 5;
  const int b = bh / NHEADS, h = bh % NHEADS;
  const int tid = threadIdx.x;
  const int w = tid >> 6, lane = tid & 63;
  const int lr = lane & 15, quad = lane >> 4;
  const int qbase = qt5 * 128 + w * 32;

  float* xw = &Xf[w][0];
  __bf16* pw = (__bf16*)xw;

  // Q fragments (B-operand): B[n = q-col = lr][k = d = quad*8+j]
  bf16x8 qf[2][2];
#pragma unroll
  for (int qt = 0; qt < 2; qt++)
#pragma unroll
    for (int kh = 0; kh < 2; kh++)
      qf[qt][kh] = *(const bf16x8*)(q + ((size_t)bh * NPAD + qbase + qt * 16 + lr) * 64 + kh * 32 + quad * 8);

  f32x4 O[2][4] = {};
  float l_p[2] = {0.0f, 0.0f};
  const float C1 = SCALE * 1.44269504089f;
  const float C0 = -8.0f * 1.44269504089f;
  const __bf16* kbase = k + (size_t)bh * NPAD * 64;
  const __bf16* vbase = vT + (size_t)bh * 64 * NPAD;

  // staging: 256 threads x 2 rounds x (K,V); dest linear (wave base + lane*16),
  // source chunk pre-swizzled: cG = cS ^ (row&7)  (involution; readers apply
  // the same XOR on their ds_read chunk).
  const int sr0 = tid >> 3, sc0 = tid & 7;            // round 0: idx = tid
  const int sr1 = (256 + tid) >> 3;                   // round 1: idx = 256+tid
  const int cg0 = sc0 ^ (sr0 & 7);
  const int cg1 = sc0 ^ (sr1 & 7);                    // idx&7 == tid&7
  auto stage = [&](int kv0, int buf) __attribute__((always_inline)) {
    gload16(kbase + (size_t)(kv0 + sr0) * 64 + cg0 * 8, &KVs[buf][tid * 8]);
    gload16(kbase + (size_t)(kv0 + sr1) * 64 + cg1 * 8, &KVs[buf][2048 + tid * 8]);
    gload16(vbase + (size_t)sr0 * NPAD + kv0 + cg0 * 8, &KVs[buf][4096 + tid * 8]);
    gload16(vbase + (size_t)sr1 * NPAD + kv0 + cg1 * 8, &KVs[buf][6144 + tid * 8]);
  };

  stage(0, 0);
  asm volatile("s_waitcnt vmcnt(0)" ::: "memory");
  asm volatile("s_barrier" ::: "memory");

  int cur = 0;
#pragma unroll 1
  for (int it = 0; it < 9; it++) {
    if (it < 8) stage((it + 1) * 64, cur ^ 1);

    // K fragments from LDS: row = nt*16+lr, chunk = (kh*4+quad)^(lr&7)
    bf16x8 kf[4][2];
#pragma unroll
    for (int nt = 0; nt < 4; nt++)
#pragma unroll
      for (int kh = 0; kh < 2; kh++)
        kf[nt][kh] = *(const bf16x8*)&KVs[cur][(nt * 16 + lr) * 64 + (((kh * 4 + quad) ^ (lr & 7)) * 8)];

    f32x4 st[2][4];
    __builtin_amdgcn_s_setprio(1);
#pragma unroll
    for (int qt = 0; qt < 2; qt++)
#pragma unroll
      for (int nt = 0; nt < 4; nt++) {
        f32x4 z = {};
        z = __builtin_amdgcn_mfma_f32_16x16x32_bf16(kf[nt][0], qf[qt][0], z, 0, 0, 0);
        z = __builtin_amdgcn_mfma_f32_16x16x32_bf16(kf[nt][1], qf[qt][1], z, 0, 0, 0);
        st[qt][nt] = z;
      }
    __builtin_amdgcn_s_setprio(0);

    // V^T fragments from LDS: row = nt2*16+lr (d), chunk = (kt*4+quad)^(lr&7)
    bf16x8 vf[4][2];
#pragma unroll
    for (int nt2 = 0; nt2 < 4; nt2++)
#pragma unroll
      for (int kt = 0; kt < 2; kt++)
        vf[nt2][kt] = *(const bf16x8*)&KVs[cur][4096 + (nt2 * 16 + lr) * 64 + (((kt * 4 + quad) ^ (lr & 7)) * 8)];

#pragma unroll
    for (int qt = 0; qt < 2; qt++) {
      float rs = 0.0f;
#pragma unroll
      for (int nt = 0; nt < 4; nt++) {
        f32x4 pv;
#pragma unroll
        for (int r = 0; r < 4; r++)
          pv[r] = __builtin_amdgcn_exp2f(st[qt][nt][r] * C1 + C0);
        rs += pv[0] + pv[1] + pv[2] + pv[3];
        bf16x4 pk = {(__bf16)pv[0], (__bf16)pv[1], (__bf16)pv[2], (__bf16)pv[3]};
        *(bf16x4*)&pw[qt * 1152 + lr * 72 + nt * 16 + quad * 4] = pk;
      }
      l_p[qt] += rs;
    }

    // P^T fragments (B-operand): B[n = q-col = lr][k = kv = quad*8+j]
    bf16x8 pf[2][2];
#pragma unroll
    for (int qt = 0; qt < 2; qt++)
#pragma unroll
      for (int kt = 0; kt < 2; kt++)
        pf[qt][kt] = *(const bf16x8*)&pw[qt * 1152 + lr * 72 + kt * 32 + quad * 8];

    __builtin_amdgcn_s_setprio(1);
#pragma unroll
    for (int qt = 0; qt < 2; qt++)
#pragma unroll
      for (int nt2 = 0; nt2 < 4; nt2++) {
        O[qt][nt2] = __builtin_amdgcn_mfma_f32_16x16x32_bf16(vf[nt2][0], pf[qt][0], O[qt][nt2], 0, 0, 0);
        O[qt][nt2] = __builtin_amdgcn_mfma_f32_16x16x32_bf16(vf[nt2][1], pf[qt][1], O[qt][nt2], 0, 0, 0);
      }
    __builtin_amdgcn_s_setprio(0);

    // staged tile landed long ago (whole compute phase in between)
    asm volatile("s_waitcnt vmcnt(0)" ::: "memory");
    asm volatile("s_barrier" ::: "memory");
    cur ^= 1;
  }

  // ---- kv = 576 tail: the only valid column of the last tile (VALU path) ----
  {
    bf16x8 k5[2];
#pragma unroll
    for (int kh = 0; kh < 2; kh++)
      k5[kh] = *(const bf16x8*)(kbase + (size_t)576 * 64 + kh * 32 + quad * 8);
    float p5[2];
#pragma unroll
    for (int qt = 0; qt < 2; qt++) {
      float s = 0.0f;
#pragma unroll
      for (int kh = 0; kh < 2; kh++)
#pragma unroll
        for (int j = 0; j < 8; j++)
          s += (float)qf[qt][kh][j] * (float)k5[kh][j];
      s += __shfl_xor(s, 16, 64);       // sum across quads -> full dot(q,k576)
      s += __shfl_xor(s, 32, 64);
      p5[qt] = __builtin_amdgcn_exp2f(s * C1 + C0);
      if (quad == 0) l_p[qt] += p5[qt]; // epilogue reduces over quads: add once
    }
#pragma unroll
    for (int nt2 = 0; nt2 < 4; nt2++)
#pragma unroll
      for (int r = 0; r < 4; r++) {
        float vv = (float)vbase[(size_t)(nt2 * 16 + quad * 4 + r) * NPAD + 576];
        O[0][nt2][r] += p5[0] * vv;
        O[1][nt2][r] += p5[1] * vv;
      }
  }

  // ---- epilogue (unchanged) ----
#pragma unroll
  for (int qt = 0; qt < 2; qt++) {
    float lf = l_p[qt];
    lf += __shfl_xor(lf, 16, 64);
    lf += __shfl_xor(lf, 32, 64);
    float inv = 1.0f / lf;
#pragma unroll
    for (int nt2 = 0; nt2 < 4; nt2++) {
      f32x4 t;
#pragma unroll
      for (int r = 0; r < 4; r++) t[r] = O[qt][nt2][r] * inv;
      *(f32x4*)&xw[lr * 68 + nt2 * 16 + quad * 4] = t;
    }
#pragma unroll
    for (int p = 0; p < 4; p++) {
      int lm = p * 4 + quad;
      int s = qbase + qt * 16 + lm;
      if (s < NSEQ) {
        f32x4 t = *(const f32x4*)&xw[lm * 68 + lr * 4];
        bf16x4 hi;
#pragma unroll
        for (int r = 0; r < 4; r++) hi[r] = (__bf16)t[r];
        size_t base = ((size_t)b * NSEQ + s) * CDIM + h * 64 + lr * 4;
        *(bf16x4*)&aoh[base] = hi;
      }
    }
  }
}

// ---------------- GEMM2: attn_out @ w_proj^T + bias (plain bf16) -----------

#define G2_NWG (6 * 145)

__launch_bounds__(256, 2)
__global__ void gemm2(const __bf16* __restrict__ A, const __bf16* __restrict__ Bw,
                      const float* __restrict__ bias, float* __restrict__ out) {
  __shared__ __bf16 As[3][128 * 32];
  __shared__ __bf16 Bs[3][128 * 32];
  const int wgid = xcd_swizzle(blockIdx.x, G2_NWG);
  const int bn = wgid % 6, bm = wgid / 6;
  const int tid = threadIdx.x;
  const int w = tid >> 6, lane = tid & 63;
  const int lr = lane & 15, quad = lane >> 4;
  const int r0 = tid >> 2;
  const int kq = (tid & 3) * 8;
  const int K = CDIM;

  f32x4 acc[4][4] = {};
  const __bf16* Ab = A + (size_t)(bm * 128 + r0) * K + kq;
  const __bf16* Bb = Bw + (size_t)(bn * 128 + r0) * K + kq;
  const int wm = (w >> 1) * 64, wn = (w & 1) * 64;

  auto stage = [&](int kt, int buf) __attribute__((always_inline)) {
    gload16(Ab + kt, &As[buf][tid * 8]);
    gload16(Ab + kt + 64 * K, &As[buf][tid * 8 + 2048]);
    gload16(Bb + kt, &Bs[buf][tid * 8]);
    gload16(Bb + kt + 64 * K, &Bs[buf][tid * 8 + 2048]);
  };

  stage(0, 0);
  stage(32, 1);
  asm volatile("s_waitcnt vmcnt(4)" ::: "memory");
  asm volatile("s_barrier" ::: "memory");

  int c0 = 0, c1 = 1, c2 = 2;
#pragma unroll 1
  for (int kt = 0; kt < K; kt += 32) {
    if (kt + 64 < K) stage(kt + 64, c2);

    bf16x8 af[4], bfr[4];
#pragma unroll
    for (int i = 0; i < 4; i++) {
      af[i]  = *(const bf16x8*)&As[c0][(wm + i * 16 + lr) * 32 + quad * 8];
      bfr[i] = *(const bf16x8*)&Bs[c0][(wn + i * 16 + lr) * 32 + quad * 8];
    }
#pragma unroll
    for (int i = 0; i < 4; i++)
#pragma unroll
      for (int j = 0; j < 4; j++)
        acc[i][j] = __builtin_amdgcn_mfma_f32_16x16x32_bf16(af[i], bfr[j], acc[i][j], 0, 0, 0);

    if (kt + 64 < K)      asm volatile("s_waitcnt vmcnt(4)" ::: "memory");
    else if (kt + 32 < K) asm volatile("s_waitcnt vmcnt(0)" ::: "memory");
    asm volatile("s_barrier" ::: "memory");

    int tmp = c0; c0 = c1; c1 = c2; c2 = tmp;
  }

#pragma unroll
  for (int i = 0; i < 4; i++)
#pragma unroll
    for (int r = 0; r < 4; r++) {
      int m = bm * 128 + wm + i * 16 + quad * 4 + r;
      if (m < M_ROWS) {
#pragma unroll
        for (int j = 0; j < 4; j++) {
          int n = bn * 128 + wn + j * 16 + lr;
          out[(size_t)m * CDIM + n] = acc[i][j][r] + bias[n];
        }
      }
    }
}

// ------------------------------ launcher -----------------------------------

extern "C" void kernel_launch(void* const* d_in, const int* in_sizes, int n_in,
                              void* d_out, int out_size, void* d_ws, size_t ws_size,
                              hipStream_t stream) {
  const float* x      = (const float*)d_in[0];
  const float* w_qkv  = (const float*)d_in[1];
  const float* w_proj = (const float*)d_in[2];
  const float* b_proj = (const float*)d_in[3];
  const float* cosp   = (const float*)d_in[4];
  const float* sinp   = (const float*)d_in[5];
  float* out = (float*)d_out;

  char* ws = (char*)d_ws;
  auto carve = [&](size_t elts) {
    __bf16* p = (__bf16*)ws;
    ws += ((elts * 2 + 255) / 256) * 256;
    return p;
  };
  __bf16* xb    = carve((size_t)M_PAD * CDIM);
  __bf16* wqkvb = carve((size_t)QKVN * CDIM);
  __bf16* wpb   = carve((size_t)CDIM * CDIM);
  __bf16* qq    = carve((size_t)BHEADS * NPAD * 64);
  __bf16* kk    = carve((size_t)BHEADS * NPAD * 64);
  __bf16* vv    = carve((size_t)BHEADS * NPAD * 64);   // vT for attn
  __bf16* aoh   = carve((size_t)M_PAD * CDIM);
  // vr (row-major V) aliases aoh: written by gemm1, consumed by vtrans
  // BEFORE attn writes aoh.
  __bf16* vr    = aoh;

  cvt_pad<<<((M_PAD * CDIM) / 4 + 255) / 256, 256, 0, stream>>>(x, xb, (long)M_ROWS * CDIM, (long)M_PAD * CDIM);
  cvt_pad<<<((QKVN * CDIM) / 4 + 255) / 256, 256, 0, stream>>>(w_qkv, wqkvb, (long)QKVN * CDIM, (long)QKVN * CDIM);
  cvt_pad<<<((CDIM * CDIM) / 4 + 255) / 256, 256, 0, stream>>>(w_proj, wpb, (long)CDIM * CDIM, (long)CDIM * CDIM);
  pad_zero<<<(BHEADS * 63 * 64 + 255) / 256, 256, 0, stream>>>(qq, kk);
  gemm1<<<G1_NWG, 256, 0, stream>>>(xb, wqkvb, qq, kk, vr, cosp, sinp);
  vtrans<<<BHEADS * 10, 256, 0, stream>>>(vr, vv);
  attn<<<AT_NWG, 256, 0, stream>>>(qq, kk, vv, aoh);
  gemm2<<<G2_NWG, 256, 0, stream>>>(aoh, wpb, b_proj, out);
}